// Round 6
// baseline (18945.847 us; speedup 1.0000x reference)
//
#include <hip/hip_runtime.h>

#define B_SZ 512
#define SEQ 96
#define PRED 48
#define TOT 144
#define CIN 7
#define DM 128
#define GDIM 384
#define KS 5

#define CSTR 132              // LDS row stride for activation buffers
#define ASUB (20*CSTR)        // floats per 20-row sub-buffer
#define WROW 136              // swizzled LDS weight row (128 + pad)
#define SWZ(o) ((o) + ((((o) >> 6)) << 2))   // bank swizzle: pad 4 every 64 floats

#define W_CONV (KS*DM*DM)            // 81920 per conv layer (layout [k][c][o])
#define OFF_WIT (3*W_CONV)           // WiT [c][384]
#define OFF_WHT (3*W_CONV + DM*GDIM) // WhT [c][384]
#define W_TOTAL (3*W_CONV + 2*DM*GDIM)

// Device-global scratch
__device__ float g_gxg[(size_t)B_SZ*TOT*GDIM];  // invariant gx cache, [b][p][384]
__device__ float g_gxe[B_SZ*12*GDIM];           // per-step edge gx, [b][12][384]
__device__ float g_wT[W_TOTAL];                 // transposed weights

// ---------------------------------------------------------------- prep
__global__ void prep_weights(const float* __restrict__ w1, const float* __restrict__ w2,
                             const float* __restrict__ w3, const float* __restrict__ Wi,
                             const float* __restrict__ Wh) {
    int tid = blockIdx.x*256 + threadIdx.x;
    if (tid < 3*W_CONV) {
        int l = tid / W_CONV, r = tid % W_CONV;
        int o = r & 127, c = (r >> 7) & 127, k = r >> 14;   // r = (k*128+c)*128+o
        const float* w = (l==0) ? w1 : ((l==1) ? w2 : w3);
        g_wT[tid] = w[o*(DM*KS) + c*KS + k];                 // src [o][c][k]
    } else if (tid < W_TOTAL) {
        int r = tid - 3*W_CONV;
        int m = r / (DM*GDIM), q = r % (DM*GDIM);
        int g = q % GDIM, c = q / GDIM;                      // dst [c][g]
        const float* W = (m==0) ? Wi : Wh;
        g_wT[tid] = W[g*DM + c];                             // src [g][c]
    }
}

// ---------------------------------------------------------------- fma helper
template<int NJ>
__device__ __forceinline__ void fma8(float (&acc)[NJ][8], int j, float a,
                                     const float4& wA, const float4& wB) {
    acc[j][0] = fmaf(a, wA.x, acc[j][0]);
    acc[j][1] = fmaf(a, wA.y, acc[j][1]);
    acc[j][2] = fmaf(a, wA.z, acc[j][2]);
    acc[j][3] = fmaf(a, wA.w, acc[j][3]);
    acc[j][4] = fmaf(a, wB.x, acc[j][4]);
    acc[j][5] = fmaf(a, wB.y, acc[j][5]);
    acc[j][6] = fmaf(a, wB.z, acc[j][6]);
    acc[j][7] = fmaf(a, wB.w, acc[j][7]);
}

// stage 8 channels of conv weights (swizzled) into wbuf — 256-thread version
__device__ __forceinline__ void stage_conv_chunk(float* __restrict__ wbuf,
                                                 const float* __restrict__ wT,
                                                 int cc, int tid) {
    const int cj = tid >> 5, oo = (tid & 31) * 4;
    #pragma unroll
    for (int k = 0; k < KS; ++k)
        *(float4*)(wbuf + (k*8 + cj)*WROW + SWZ(oo)) =
            *(const float4*)(wT + (k*DM + cc*8 + cj)*DM + oo);
}

// Chunked in-place conv layer (init kernel, 256 threads).
template<int NJ>
__device__ __forceinline__ void conv_layer_chunked(float* __restrict__ buf,
                                                   float* __restrict__ wbuf,
                                                   const float* __restrict__ wT,
                                                   const float* __restrict__ bias,
                                                   int nrow, int winO, int tid) {
    const int og = tid & 15, ttg = tid >> 4;
    const int o0 = og*8, so0 = SWZ(o0), r0 = ttg*NJ;
    const bool act = (r0 < nrow);
    float acc[NJ][8];
    #pragma unroll
    for (int u = 0; u < 8; ++u) {
        float bv = bias[o0+u];
        #pragma unroll
        for (int j = 0; j < NJ; ++j) acc[j][u] = bv;
    }
    for (int cc = 0; cc < DM/8; ++cc) {
        __syncthreads();
        stage_conv_chunk(wbuf, wT, cc, tid);
        __syncthreads();
        if (act) {
            const int c0 = cc*8;
            #pragma unroll
            for (int cj = 0; cj < 8; cj += 2) {
                float2 a2[NJ+4];
                #pragma unroll
                for (int m = 0; m < NJ+4; ++m)
                    a2[m] = *(const float2*)(buf + (r0+m)*CSTR + c0 + cj);
                #pragma unroll
                for (int k = 0; k < KS; ++k) {
                    const float4 wA0 = *(const float4*)(wbuf + (k*8+cj)*WROW + so0);
                    const float4 wB0 = *(const float4*)(wbuf + (k*8+cj)*WROW + so0 + 4);
                    const float4 wA1 = *(const float4*)(wbuf + (k*8+cj+1)*WROW + so0);
                    const float4 wB1 = *(const float4*)(wbuf + (k*8+cj+1)*WROW + so0 + 4);
                    #pragma unroll
                    for (int j = 0; j < NJ; ++j) {
                        fma8(acc, j, a2[j+k].x, wA0, wB0);
                        fma8(acc, j, a2[j+k].y, wA1, wB1);
                    }
                }
            }
        }
    }
    __syncthreads();
    if (act) {
        #pragma unroll
        for (int j = 0; j < NJ; ++j) {
            int q = r0 + j, w = winO + q;
            bool valid = (w >= 0) && (w < SEQ);
            #pragma unroll
            for (int u = 0; u < 8; ++u)
                buf[q*CSTR + o0+u] = valid ? fmaxf(acc[j][u], 0.f) : 0.f;
        }
    }
    __syncthreads();
}

// ------------------------------------------------------------- init kernel
// Step 0's full conv cascade; stores invariant gx rows w in [6,90) to g_gxg[b][w].
__launch_bounds__(256, 3)
__global__ void init_kernel(const float* __restrict__ x_enc,
                            const int* __restrict__ y_mark,
                            const float* __restrict__ hour_e, const float* __restrict__ wk_e,
                            const float* __restrict__ day_e, const float* __restrict__ mon_e,
                            const float* __restrict__ W_val, const float* __restrict__ b_val,
                            const float* __restrict__ b1, const float* __restrict__ b2,
                            const float* __restrict__ b3, const float* __restrict__ gbi) {
    __shared__ float buf[60*CSTR];
    __shared__ float wbuf[KS*8*WROW];
    const int tid = threadIdx.x;
    const int b = blockIdx.x;
    const int cs = blockIdx.y * 48;

    for (int e = tid; e < 60*DM; e += 256) {
        int q = e >> 7, d = e & 127;
        int w = cs - 6 + q;
        float v = 0.f;
        if (w >= 0 && w < SEQ) {
            const float* xr = x_enc + (b*SEQ + w)*CIN;
            v = b_val[d];
            #pragma unroll
            for (int c = 0; c < CIN; ++c) v = fmaf(xr[c], W_val[d*CIN + c], v);
            const int* ym = y_mark + (b*TOT + w)*4;
            v += hour_e[ym[0]*DM + d] + wk_e[ym[1]*DM + d]
               + day_e[ym[2]*DM + d] + mon_e[ym[3]*DM + d];
        }
        buf[q*CSTR + d] = v;
    }
    conv_layer_chunked<4>(buf, wbuf, g_wT,            b1, 56, cs - 4, tid);
    conv_layer_chunked<4>(buf, wbuf, g_wT + W_CONV,   b2, 52, cs - 2, tid);
    conv_layer_chunked<3>(buf, wbuf, g_wT + 2*W_CONV, b3, 48, cs,     tid);

    const int og = tid & 15, ttg = tid >> 4;
    const int g0 = og*24, r0 = ttg*3;
    const float* WiT = g_wT + OFF_WIT;
    float ga[3][24];
    #pragma unroll
    for (int e = 0; e < 24; ++e) {
        float bv = gbi[g0+e];
        #pragma unroll
        for (int j = 0; j < 3; ++j) ga[j][e] = bv;
    }
    for (int cc = 0; cc < DM/8; ++cc) {
        __syncthreads();
        #pragma unroll
        for (int s = 0; s < 3; ++s)
            ((float4*)wbuf)[s*256 + tid] = ((const float4*)(WiT + cc*8*GDIM))[s*256 + tid];
        __syncthreads();
        const int c0 = cc*8;
        #pragma unroll
        for (int cj = 0; cj < 8; cj += 2) {
            float2 a2[3];
            #pragma unroll
            for (int m = 0; m < 3; ++m)
                a2[m] = *(const float2*)(buf + (r0+m)*CSTR + c0 + cj);
            float4 w4[6];
            #pragma unroll
            for (int q = 0; q < 6; ++q)
                w4[q] = *(const float4*)(wbuf + cj*GDIM + g0 + q*4);
            const float* wv = (const float*)w4;
            #pragma unroll
            for (int j = 0; j < 3; ++j)
                #pragma unroll
                for (int e = 0; e < 24; ++e)
                    ga[j][e] = fmaf(a2[j].x, wv[e], ga[j][e]);
            #pragma unroll
            for (int q = 0; q < 6; ++q)
                w4[q] = *(const float4*)(wbuf + (cj+1)*GDIM + g0 + q*4);
            #pragma unroll
            for (int j = 0; j < 3; ++j)
                #pragma unroll
                for (int e = 0; e < 24; ++e)
                    ga[j][e] = fmaf(a2[j].y, wv[e], ga[j][e]);
        }
    }
    #pragma unroll
    for (int j = 0; j < 3; ++j) {
        int w = cs + r0 + j;
        if (w >= 6 && w < 90) {
            float* gxo = g_gxg + ((size_t)b*TOT + w)*GDIM + g0;
            #pragma unroll
            for (int q = 0; q < 6; ++q)
                *(float4*)(gxo + q*4) = *(const float4*)&ga[j][q*4];
        }
    }
}

// ------------------------------------------------------------- step layer
// 256 threads, 2 sub-buffers (left/right edge of one batch). R rows/sub.
template<int NJ>
__device__ __forceinline__ void mlayer(float* __restrict__ abuf, float* __restrict__ wbuf,
                                       const float* __restrict__ wT,
                                       const float* __restrict__ bias,
                                       int R, int off, int tid) {
    const int og = tid & 15, ttg = tid >> 4;     // og 0..15, ttg 0..15
    const int o0 = og*8, so0 = SWZ(o0);
    const int m0 = ttg * NJ;
    const bool act = (m0 < 2*R);
    int s = 0, r0 = 0;
    if (act) { s = m0 / R; r0 = m0 - s*R; }      // NJ divides R -> rows don't span subs
    float* in = abuf + s*ASUB;
    float acc[NJ][8];
    #pragma unroll
    for (int u = 0; u < 8; ++u) {
        float bv = bias[o0+u];
        #pragma unroll
        for (int j = 0; j < NJ; ++j) acc[j][u] = bv;
    }
    for (int cc = 0; cc < DM/8; ++cc) {
        __syncthreads();
        stage_conv_chunk(wbuf, wT, cc, tid);
        __syncthreads();
        if (act) {
            const int c0 = cc*8;
            #pragma unroll
            for (int cj = 0; cj < 8; cj += 2) {
                float2 a2[NJ+4];
                #pragma unroll
                for (int m = 0; m < NJ+4; ++m)
                    a2[m] = *(const float2*)(in + (r0+m)*CSTR + c0 + cj);
                #pragma unroll
                for (int k = 0; k < KS; ++k) {
                    const float4 wA0 = *(const float4*)(wbuf + (k*8+cj)*WROW + so0);
                    const float4 wB0 = *(const float4*)(wbuf + (k*8+cj)*WROW + so0 + 4);
                    const float4 wA1 = *(const float4*)(wbuf + (k*8+cj+1)*WROW + so0);
                    const float4 wB1 = *(const float4*)(wbuf + (k*8+cj+1)*WROW + so0 + 4);
                    #pragma unroll
                    for (int j = 0; j < NJ; ++j) {
                        fma8(acc, j, a2[j+k].x, wA0, wB0);
                        fma8(acc, j, a2[j+k].y, wA1, wB1);
                    }
                }
            }
        }
    }
    __syncthreads();
    if (act) {
        const int wb = s ? 83 : -6;
        #pragma unroll
        for (int j = 0; j < NJ; ++j) {
            int q = r0 + j, w = wb + off + q;
            bool valid = (w >= 0) && (w < SEQ);
            #pragma unroll
            for (int u = 0; u < 8; ++u)
                in[q*CSTR + o0+u] = valid ? fmaxf(acc[j][u], 0.f) : 0.f;
        }
    }
    __syncthreads();
}

// ------------------------------------------------------------- step kernel
// grid 512, 256 threads. Block handles one batch x both edges (2 subs).
__launch_bounds__(256, 3)
__global__ void step_kernel(int i, const float* __restrict__ x_enc,
                            const int* __restrict__ y_mark,
                            const float* __restrict__ hour_e, const float* __restrict__ wk_e,
                            const float* __restrict__ day_e, const float* __restrict__ mon_e,
                            const float* __restrict__ W_val, const float* __restrict__ b_val,
                            const float* __restrict__ b1, const float* __restrict__ b2,
                            const float* __restrict__ b3, const float* __restrict__ gbi,
                            const float* __restrict__ out) {
    __shared__ float abuf[2*ASUB];     // 21.1 KB
    __shared__ float wbuf[16*GDIM];    // 24.6 KB (conv chunks use 5440 floats of it)
    const int tid = threadIdx.x;
    const int b = blockIdx.x;

    // ---- embedding: 2 subs x 20 rows x 128
    for (int e = tid; e < 2*20*DM; e += 256) {
        int s = e / (20*DM);
        int rem = e - s*(20*DM);
        int q = rem >> 7, d = rem & 127;
        int wb = s ? 83 : -6;
        int w = wb + q;
        float v = 0.f;
        if (w >= 0 && w < SEQ) {
            int p = i + w;
            const float* xr = (p < SEQ) ? (x_enc + (b*SEQ + p)*CIN)
                                        : (out + (b*PRED + (p - SEQ))*CIN);
            v = b_val[d];
            #pragma unroll
            for (int c = 0; c < CIN; ++c) v = fmaf(xr[c], W_val[d*CIN + c], v);
            const int* ym = y_mark + (b*TOT + p)*4;
            v += hour_e[ym[0]*DM + d] + wk_e[ym[1]*DM + d]
               + day_e[ym[2]*DM + d] + mon_e[ym[3]*DM + d];
        }
        abuf[s*ASUB + q*CSTR + d] = v;
    }
    mlayer<2>(abuf, wbuf, g_wT,            b1, 16, 2, tid);  // c1: 32 rows
    mlayer<2>(abuf, wbuf, g_wT + W_CONV,   b2, 12, 4, tid);  // c2: 24 rows
    mlayer<1>(abuf, wbuf, g_wT + 2*W_CONV, b3,  8, 6, tid);  // c3: 16 rows

    // ---- gx: 16 c3 rows; thread tile = 2 rows x 12 g
    const int mp = tid >> 5;                 // 0..7 row-pairs
    const int g0 = (tid & 31) * 12;
    const int s = mp >> 2;                   // sub-buffer
    const int row0 = (2*mp) & 7;
    const float* a0p = abuf + s*ASUB + row0*CSTR;
    const float* a1p = a0p + CSTR;
    const float* WiT = g_wT + OFF_WIT;
    float ga[2][12];
    #pragma unroll
    for (int e = 0; e < 12; ++e) { float bv = gbi[g0+e]; ga[0][e] = bv; ga[1][e] = bv; }
    for (int cc = 0; cc < 8; ++cc) {
        __syncthreads();
        for (int x = tid; x < 16*GDIM/4; x += 256)
            ((float4*)wbuf)[x] = ((const float4*)(WiT + cc*16*GDIM))[x];
        __syncthreads();
        #pragma unroll
        for (int c = 0; c < 16; ++c) {
            float av0 = a0p[cc*16 + c];
            float av1 = a1p[cc*16 + c];
            const float* wr = wbuf + c*GDIM + g0;
            #pragma unroll
            for (int q4 = 0; q4 < 3; ++q4) {
                float4 w4 = *(const float4*)(wr + q4*4);
                ga[0][q4*4+0] = fmaf(av0, w4.x, ga[0][q4*4+0]);
                ga[0][q4*4+1] = fmaf(av0, w4.y, ga[0][q4*4+1]);
                ga[0][q4*4+2] = fmaf(av0, w4.z, ga[0][q4*4+2]);
                ga[0][q4*4+3] = fmaf(av0, w4.w, ga[0][q4*4+3]);
                ga[1][q4*4+0] = fmaf(av1, w4.x, ga[1][q4*4+0]);
                ga[1][q4*4+1] = fmaf(av1, w4.y, ga[1][q4*4+1]);
                ga[1][q4*4+2] = fmaf(av1, w4.z, ga[1][q4*4+2]);
                ga[1][q4*4+3] = fmaf(av1, w4.w, ga[1][q4*4+3]);
            }
        }
    }
    const int wb = s ? 83 : -6;
    #pragma unroll
    for (int j = 0; j < 2; ++j) {
        int w = wb + 6 + row0 + j;
        float* dst = nullptr;
        if (s == 0) {
            if (w < 6) dst = g_gxe + ((size_t)b*12 + w)*GDIM + g0;
        } else {
            if (w == 89)      dst = g_gxg + ((size_t)b*TOT + (i + 89))*GDIM + g0;
            else if (w < SEQ) dst = g_gxe + ((size_t)b*12 + (w - 84))*GDIM + g0;
        }
        if (dst) {
            *(float4*)(dst)     = *(const float4*)&ga[j][0];
            *(float4*)(dst + 4) = *(const float4*)&ga[j][4];
            *(float4*)(dst + 8) = *(const float4*)&ga[j][8];
        }
    }
}

// -------------------------------------------------------------- recurrence
// grid 512, 128 threads (2 waves): thread j owns hidden unit j, all 3 gates.
// Wh rows (r,z,n) for unit j in 384 VGPRs; launch_bounds(128,1) -> 512 budget.
// One barrier per t via ping-pong H. LDS traffic: 64 b128 reads/block/t.
__launch_bounds__(128, 1)
__global__ void gru_rec(int i, const float* __restrict__ gbh,
                        const float* __restrict__ fc_w, const float* __restrict__ fc_b,
                        float* __restrict__ out) {
    __shared__ __align__(16) float H[2][DM];
    const int j = threadIdx.x;
    const int b = blockIdx.x;
    const float* WhT = g_wT + OFF_WHT;

    float whr[DM], whz[DM], whn[DM];
    #pragma unroll
    for (int c = 0; c < DM; ++c) {
        whr[c] = WhT[c*GDIM + j];
        whz[c] = WhT[c*GDIM + DM + j];
        whn[c] = WhT[c*GDIM + 2*DM + j];
    }
    const float bhr = gbh[j], bhz = gbh[DM + j], bhn = gbh[2*DM + j];
    float h = 0.f;
    H[0][j] = 0.f;
    __syncthreads();

    const float* gxg_b = g_gxg + (size_t)b*TOT*GDIM;
    const float* gxe_b = g_gxe + (size_t)b*12*GDIM;
    auto gp = [&](int t) -> const float* {
        return (t < 6)  ? (gxe_b + t*GDIM)
             : (t < 90) ? (gxg_b + (size_t)(i + t)*GDIM)
                        : (gxe_b + (t - 84)*GDIM);
    };

    const float* g0p = gp(0);
    float gxr = g0p[j], gxz = g0p[DM + j], gxn = g0p[2*DM + j];
    for (int t = 0; t < SEQ; ++t) {
        float nxr = 0.f, nxz = 0.f, nxn = 0.f;
        if (t + 1 < SEQ) {                      // prefetch next t's gate inputs
            const float* gq = gp(t + 1);
            nxr = gq[j]; nxz = gq[DM + j]; nxn = gq[2*DM + j];
        }
        const float* Hc = H[t & 1];
        float ar = bhr, az = bhz, an = bhn;     // 3 chains, 6-cyc dep distance
        #pragma unroll
        for (int c = 0; c < DM; c += 4) {
            float4 h4 = *(const float4*)(Hc + c);   // wave-uniform broadcast
            ar = fmaf(h4.x, whr[c],   ar); az = fmaf(h4.x, whz[c],   az); an = fmaf(h4.x, whn[c],   an);
            ar = fmaf(h4.y, whr[c+1], ar); az = fmaf(h4.y, whz[c+1], az); an = fmaf(h4.y, whn[c+1], an);
            ar = fmaf(h4.z, whr[c+2], ar); az = fmaf(h4.z, whz[c+2], az); an = fmaf(h4.z, whn[c+2], an);
            ar = fmaf(h4.w, whr[c+3], ar); az = fmaf(h4.w, whz[c+3], az); an = fmaf(h4.w, whn[c+3], an);
        }
        float r = 1.f/(1.f + __expf(-(gxr + ar)));
        float z = 1.f/(1.f + __expf(-(gxz + az)));
        float xn = gxn + r*an;
        float e2 = __expf(2.f*xn);
        float n = 1.f - 2.f/(e2 + 1.f);         // tanh(xn)
        h = (1.f - z)*n + z*h;
        H[(t+1) & 1][j] = h;
        __syncthreads();
        gxr = nxr; gxz = nxz; gxn = nxn;
    }

    if (j < CIN) {
        float p = fc_b[j];
        const float* Hf = H[SEQ & 1];           // SEQ even -> H[0]
        #pragma unroll
        for (int d = 0; d < DM; ++d) p = fmaf(fc_w[j*DM + d], Hf[d], p);
        out[(b*PRED + i)*CIN + j] = p;
    }
}

// ---------------------------------------------------------------- launch
extern "C" void kernel_launch(void* const* d_in, const int* in_sizes, int n_in,
                              void* d_out, int out_size, void* d_ws, size_t ws_size,
                              hipStream_t stream) {
    const float* x_enc  = (const float*)d_in[0];
    const int*   y_mark = (const int*)d_in[2];
    const float* hour_e = (const float*)d_in[3];
    const float* wk_e   = (const float*)d_in[4];
    const float* day_e  = (const float*)d_in[5];
    const float* mon_e  = (const float*)d_in[6];
    const float* W_val  = (const float*)d_in[7];
    const float* b_val  = (const float*)d_in[8];
    const float* c1w    = (const float*)d_in[9];
    const float* c1b    = (const float*)d_in[10];
    const float* c2w    = (const float*)d_in[11];
    const float* c2b    = (const float*)d_in[12];
    const float* c3w    = (const float*)d_in[13];
    const float* c3b    = (const float*)d_in[14];
    const float* Wi     = (const float*)d_in[15];
    const float* Wh     = (const float*)d_in[16];
    const float* gbi    = (const float*)d_in[17];
    const float* gbh    = (const float*)d_in[18];
    const float* fcw    = (const float*)d_in[19];
    const float* fcb    = (const float*)d_in[20];
    float* out = (float*)d_out;

    prep_weights<<<(W_TOTAL + 255)/256, 256, 0, stream>>>(c1w, c2w, c3w, Wi, Wh);

    init_kernel<<<dim3(B_SZ, 2), 256, 0, stream>>>(x_enc, y_mark,
        hour_e, wk_e, day_e, mon_e, W_val, b_val, c1b, c2b, c3b, gbi);

    for (int i = 0; i < PRED; ++i) {
        step_kernel<<<B_SZ, 256, 0, stream>>>(i, x_enc, y_mark,
            hour_e, wk_e, day_e, mon_e, W_val, b_val, c1b, c2b, c3b, gbi, out);
        gru_rec<<<B_SZ, 128, 0, stream>>>(i, gbh, fcw, fcb, out);
    }
}

// Round 7
// 18895.650 us; speedup vs baseline: 1.0027x; 1.0027x over previous
//
#include <hip/hip_runtime.h>

#define B_SZ 512
#define SEQ 96
#define PRED 48
#define TOT 144
#define CIN 7
#define DM 128
#define GDIM 384
#define KS 5

#define CSTR 132              // LDS row stride for activation buffers
#define ASUB (20*CSTR)        // floats per 20-row sub-buffer
#define WROW 136              // swizzled LDS weight row (128 + pad)
#define SWZ(o) ((o) + ((((o) >> 6)) << 2))   // bank swizzle: pad 4 every 64 floats

#define W_CONV (KS*DM*DM)            // 81920 per conv layer (layout [k][c][o])
#define OFF_WIT (3*W_CONV)           // WiT [c][384]
#define OFF_WHT (3*W_CONV + DM*GDIM) // WhT [c][384]
#define W_TOTAL (3*W_CONV + 2*DM*GDIM)

typedef float f32x32 __attribute__((ext_vector_type(32)));

// Device-global scratch
__device__ float g_gxg[(size_t)B_SZ*TOT*GDIM];  // invariant gx cache, [b][p][384]
__device__ float g_gxe[B_SZ*12*GDIM];           // per-step edge gx, [b][12][384]
__device__ float g_wT[W_TOTAL];                 // transposed weights

// ---------------------------------------------------------------- prep
__global__ void prep_weights(const float* __restrict__ w1, const float* __restrict__ w2,
                             const float* __restrict__ w3, const float* __restrict__ Wi,
                             const float* __restrict__ Wh) {
    int tid = blockIdx.x*256 + threadIdx.x;
    if (tid < 3*W_CONV) {
        int l = tid / W_CONV, r = tid % W_CONV;
        int o = r & 127, c = (r >> 7) & 127, k = r >> 14;   // r = (k*128+c)*128+o
        const float* w = (l==0) ? w1 : ((l==1) ? w2 : w3);
        g_wT[tid] = w[o*(DM*KS) + c*KS + k];                 // src [o][c][k]
    } else if (tid < W_TOTAL) {
        int r = tid - 3*W_CONV;
        int m = r / (DM*GDIM), q = r % (DM*GDIM);
        int g = q % GDIM, c = q / GDIM;                      // dst [c][g]
        const float* W = (m==0) ? Wi : Wh;
        g_wT[tid] = W[g*DM + c];                             // src [g][c]
    }
}

// ---------------------------------------------------------------- fma helper
template<int NJ>
__device__ __forceinline__ void fma8(float (&acc)[NJ][8], int j, float a,
                                     const float4& wA, const float4& wB) {
    acc[j][0] = fmaf(a, wA.x, acc[j][0]);
    acc[j][1] = fmaf(a, wA.y, acc[j][1]);
    acc[j][2] = fmaf(a, wA.z, acc[j][2]);
    acc[j][3] = fmaf(a, wA.w, acc[j][3]);
    acc[j][4] = fmaf(a, wB.x, acc[j][4]);
    acc[j][5] = fmaf(a, wB.y, acc[j][5]);
    acc[j][6] = fmaf(a, wB.z, acc[j][6]);
    acc[j][7] = fmaf(a, wB.w, acc[j][7]);
}

// stage 8 channels of conv weights (swizzled) into wbuf — 256-thread version
__device__ __forceinline__ void stage_conv_chunk(float* __restrict__ wbuf,
                                                 const float* __restrict__ wT,
                                                 int cc, int tid) {
    const int cj = tid >> 5, oo = (tid & 31) * 4;
    #pragma unroll
    for (int k = 0; k < KS; ++k)
        *(float4*)(wbuf + (k*8 + cj)*WROW + SWZ(oo)) =
            *(const float4*)(wT + (k*DM + cc*8 + cj)*DM + oo);
}

// Chunked in-place conv layer (init kernel, 256 threads).
template<int NJ>
__device__ __forceinline__ void conv_layer_chunked(float* __restrict__ buf,
                                                   float* __restrict__ wbuf,
                                                   const float* __restrict__ wT,
                                                   const float* __restrict__ bias,
                                                   int nrow, int winO, int tid) {
    const int og = tid & 15, ttg = tid >> 4;
    const int o0 = og*8, so0 = SWZ(o0), r0 = ttg*NJ;
    const bool act = (r0 < nrow);
    float acc[NJ][8];
    #pragma unroll
    for (int u = 0; u < 8; ++u) {
        float bv = bias[o0+u];
        #pragma unroll
        for (int j = 0; j < NJ; ++j) acc[j][u] = bv;
    }
    for (int cc = 0; cc < DM/8; ++cc) {
        __syncthreads();
        stage_conv_chunk(wbuf, wT, cc, tid);
        __syncthreads();
        if (act) {
            const int c0 = cc*8;
            #pragma unroll
            for (int cj = 0; cj < 8; cj += 2) {
                float2 a2[NJ+4];
                #pragma unroll
                for (int m = 0; m < NJ+4; ++m)
                    a2[m] = *(const float2*)(buf + (r0+m)*CSTR + c0 + cj);
                #pragma unroll
                for (int k = 0; k < KS; ++k) {
                    const float4 wA0 = *(const float4*)(wbuf + (k*8+cj)*WROW + so0);
                    const float4 wB0 = *(const float4*)(wbuf + (k*8+cj)*WROW + so0 + 4);
                    const float4 wA1 = *(const float4*)(wbuf + (k*8+cj+1)*WROW + so0);
                    const float4 wB1 = *(const float4*)(wbuf + (k*8+cj+1)*WROW + so0 + 4);
                    #pragma unroll
                    for (int j = 0; j < NJ; ++j) {
                        fma8(acc, j, a2[j+k].x, wA0, wB0);
                        fma8(acc, j, a2[j+k].y, wA1, wB1);
                    }
                }
            }
        }
    }
    __syncthreads();
    if (act) {
        #pragma unroll
        for (int j = 0; j < NJ; ++j) {
            int q = r0 + j, w = winO + q;
            bool valid = (w >= 0) && (w < SEQ);
            #pragma unroll
            for (int u = 0; u < 8; ++u)
                buf[q*CSTR + o0+u] = valid ? fmaxf(acc[j][u], 0.f) : 0.f;
        }
    }
    __syncthreads();
}

// ------------------------------------------------------------- init kernel
// Step 0's full conv cascade; stores invariant gx rows w in [6,90) to g_gxg[b][w].
__launch_bounds__(256, 3)
__global__ void init_kernel(const float* __restrict__ x_enc,
                            const int* __restrict__ y_mark,
                            const float* __restrict__ hour_e, const float* __restrict__ wk_e,
                            const float* __restrict__ day_e, const float* __restrict__ mon_e,
                            const float* __restrict__ W_val, const float* __restrict__ b_val,
                            const float* __restrict__ b1, const float* __restrict__ b2,
                            const float* __restrict__ b3, const float* __restrict__ gbi) {
    __shared__ float buf[60*CSTR];
    __shared__ float wbuf[KS*8*WROW];
    const int tid = threadIdx.x;
    const int b = blockIdx.x;
    const int cs = blockIdx.y * 48;

    for (int e = tid; e < 60*DM; e += 256) {
        int q = e >> 7, d = e & 127;
        int w = cs - 6 + q;
        float v = 0.f;
        if (w >= 0 && w < SEQ) {
            const float* xr = x_enc + (b*SEQ + w)*CIN;
            v = b_val[d];
            #pragma unroll
            for (int c = 0; c < CIN; ++c) v = fmaf(xr[c], W_val[d*CIN + c], v);
            const int* ym = y_mark + (b*TOT + w)*4;
            v += hour_e[ym[0]*DM + d] + wk_e[ym[1]*DM + d]
               + day_e[ym[2]*DM + d] + mon_e[ym[3]*DM + d];
        }
        buf[q*CSTR + d] = v;
    }
    conv_layer_chunked<4>(buf, wbuf, g_wT,            b1, 56, cs - 4, tid);
    conv_layer_chunked<4>(buf, wbuf, g_wT + W_CONV,   b2, 52, cs - 2, tid);
    conv_layer_chunked<3>(buf, wbuf, g_wT + 2*W_CONV, b3, 48, cs,     tid);

    const int og = tid & 15, ttg = tid >> 4;
    const int g0 = og*24, r0 = ttg*3;
    const float* WiT = g_wT + OFF_WIT;
    float ga[3][24];
    #pragma unroll
    for (int e = 0; e < 24; ++e) {
        float bv = gbi[g0+e];
        #pragma unroll
        for (int j = 0; j < 3; ++j) ga[j][e] = bv;
    }
    for (int cc = 0; cc < DM/8; ++cc) {
        __syncthreads();
        #pragma unroll
        for (int s = 0; s < 3; ++s)
            ((float4*)wbuf)[s*256 + tid] = ((const float4*)(WiT + cc*8*GDIM))[s*256 + tid];
        __syncthreads();
        const int c0 = cc*8;
        #pragma unroll
        for (int cj = 0; cj < 8; cj += 2) {
            float2 a2[3];
            #pragma unroll
            for (int m = 0; m < 3; ++m)
                a2[m] = *(const float2*)(buf + (r0+m)*CSTR + c0 + cj);
            float4 w4[6];
            #pragma unroll
            for (int q = 0; q < 6; ++q)
                w4[q] = *(const float4*)(wbuf + cj*GDIM + g0 + q*4);
            const float* wv = (const float*)w4;
            #pragma unroll
            for (int j = 0; j < 3; ++j)
                #pragma unroll
                for (int e = 0; e < 24; ++e)
                    ga[j][e] = fmaf(a2[j].x, wv[e], ga[j][e]);
            #pragma unroll
            for (int q = 0; q < 6; ++q)
                w4[q] = *(const float4*)(wbuf + (cj+1)*GDIM + g0 + q*4);
            #pragma unroll
            for (int j = 0; j < 3; ++j)
                #pragma unroll
                for (int e = 0; e < 24; ++e)
                    ga[j][e] = fmaf(a2[j].y, wv[e], ga[j][e]);
        }
    }
    #pragma unroll
    for (int j = 0; j < 3; ++j) {
        int w = cs + r0 + j;
        if (w >= 6 && w < 90) {
            float* gxo = g_gxg + ((size_t)b*TOT + w)*GDIM + g0;
            #pragma unroll
            for (int q = 0; q < 6; ++q)
                *(float4*)(gxo + q*4) = *(const float4*)&ga[j][q*4];
        }
    }
}

// ------------------------------------------------------------- step layer
// 256 threads, 2 sub-buffers (left/right edge of one batch). R rows/sub.
template<int NJ>
__device__ __forceinline__ void mlayer(float* __restrict__ abuf, float* __restrict__ wbuf,
                                       const float* __restrict__ wT,
                                       const float* __restrict__ bias,
                                       int R, int off, int tid) {
    const int og = tid & 15, ttg = tid >> 4;     // og 0..15, ttg 0..15
    const int o0 = og*8, so0 = SWZ(o0);
    const int m0 = ttg * NJ;
    const bool act = (m0 < 2*R);
    int s = 0, r0 = 0;
    if (act) { s = m0 / R; r0 = m0 - s*R; }      // NJ divides R -> rows don't span subs
    float* in = abuf + s*ASUB;
    float acc[NJ][8];
    #pragma unroll
    for (int u = 0; u < 8; ++u) {
        float bv = bias[o0+u];
        #pragma unroll
        for (int j = 0; j < NJ; ++j) acc[j][u] = bv;
    }
    for (int cc = 0; cc < DM/8; ++cc) {
        __syncthreads();
        stage_conv_chunk(wbuf, wT, cc, tid);
        __syncthreads();
        if (act) {
            const int c0 = cc*8;
            #pragma unroll
            for (int cj = 0; cj < 8; cj += 2) {
                float2 a2[NJ+4];
                #pragma unroll
                for (int m = 0; m < NJ+4; ++m)
                    a2[m] = *(const float2*)(in + (r0+m)*CSTR + c0 + cj);
                #pragma unroll
                for (int k = 0; k < KS; ++k) {
                    const float4 wA0 = *(const float4*)(wbuf + (k*8+cj)*WROW + so0);
                    const float4 wB0 = *(const float4*)(wbuf + (k*8+cj)*WROW + so0 + 4);
                    const float4 wA1 = *(const float4*)(wbuf + (k*8+cj+1)*WROW + so0);
                    const float4 wB1 = *(const float4*)(wbuf + (k*8+cj+1)*WROW + so0 + 4);
                    #pragma unroll
                    for (int j = 0; j < NJ; ++j) {
                        fma8(acc, j, a2[j+k].x, wA0, wB0);
                        fma8(acc, j, a2[j+k].y, wA1, wB1);
                    }
                }
            }
        }
    }
    __syncthreads();
    if (act) {
        const int wb = s ? 83 : -6;
        #pragma unroll
        for (int j = 0; j < NJ; ++j) {
            int q = r0 + j, w = wb + off + q;
            bool valid = (w >= 0) && (w < SEQ);
            #pragma unroll
            for (int u = 0; u < 8; ++u)
                in[q*CSTR + o0+u] = valid ? fmaxf(acc[j][u], 0.f) : 0.f;
        }
    }
    __syncthreads();
}

// ------------------------------------------------------------- step kernel
// grid 512, 256 threads. Block handles one batch x both edges (2 subs).
__launch_bounds__(256, 3)
__global__ void step_kernel(int i, const float* __restrict__ x_enc,
                            const int* __restrict__ y_mark,
                            const float* __restrict__ hour_e, const float* __restrict__ wk_e,
                            const float* __restrict__ day_e, const float* __restrict__ mon_e,
                            const float* __restrict__ W_val, const float* __restrict__ b_val,
                            const float* __restrict__ b1, const float* __restrict__ b2,
                            const float* __restrict__ b3, const float* __restrict__ gbi,
                            const float* __restrict__ out) {
    __shared__ float abuf[2*ASUB];     // 21.1 KB
    __shared__ float wbuf[16*GDIM];    // 24.6 KB (conv chunks use 5440 floats of it)
    const int tid = threadIdx.x;
    const int b = blockIdx.x;

    // ---- embedding: 2 subs x 20 rows x 128
    for (int e = tid; e < 2*20*DM; e += 256) {
        int s = e / (20*DM);
        int rem = e - s*(20*DM);
        int q = rem >> 7, d = rem & 127;
        int wb = s ? 83 : -6;
        int w = wb + q;
        float v = 0.f;
        if (w >= 0 && w < SEQ) {
            int p = i + w;
            const float* xr = (p < SEQ) ? (x_enc + (b*SEQ + p)*CIN)
                                        : (out + (b*PRED + (p - SEQ))*CIN);
            v = b_val[d];
            #pragma unroll
            for (int c = 0; c < CIN; ++c) v = fmaf(xr[c], W_val[d*CIN + c], v);
            const int* ym = y_mark + (b*TOT + p)*4;
            v += hour_e[ym[0]*DM + d] + wk_e[ym[1]*DM + d]
               + day_e[ym[2]*DM + d] + mon_e[ym[3]*DM + d];
        }
        abuf[s*ASUB + q*CSTR + d] = v;
    }
    mlayer<2>(abuf, wbuf, g_wT,            b1, 16, 2, tid);  // c1: 32 rows
    mlayer<2>(abuf, wbuf, g_wT + W_CONV,   b2, 12, 4, tid);  // c2: 24 rows
    mlayer<1>(abuf, wbuf, g_wT + 2*W_CONV, b3,  8, 6, tid);  // c3: 16 rows

    // ---- gx: 16 c3 rows; thread tile = 2 rows x 12 g
    const int mp = tid >> 5;                 // 0..7 row-pairs
    const int g0 = (tid & 31) * 12;
    const int s = mp >> 2;                   // sub-buffer
    const int row0 = (2*mp) & 7;
    const float* a0p = abuf + s*ASUB + row0*CSTR;
    const float* a1p = a0p + CSTR;
    const float* WiT = g_wT + OFF_WIT;
    float ga[2][12];
    #pragma unroll
    for (int e = 0; e < 12; ++e) { float bv = gbi[g0+e]; ga[0][e] = bv; ga[1][e] = bv; }
    for (int cc = 0; cc < 8; ++cc) {
        __syncthreads();
        for (int x = tid; x < 16*GDIM/4; x += 256)
            ((float4*)wbuf)[x] = ((const float4*)(WiT + cc*16*GDIM))[x];
        __syncthreads();
        #pragma unroll
        for (int c = 0; c < 16; ++c) {
            float av0 = a0p[cc*16 + c];
            float av1 = a1p[cc*16 + c];
            const float* wr = wbuf + c*GDIM + g0;
            #pragma unroll
            for (int q4 = 0; q4 < 3; ++q4) {
                float4 w4 = *(const float4*)(wr + q4*4);
                ga[0][q4*4+0] = fmaf(av0, w4.x, ga[0][q4*4+0]);
                ga[0][q4*4+1] = fmaf(av0, w4.y, ga[0][q4*4+1]);
                ga[0][q4*4+2] = fmaf(av0, w4.z, ga[0][q4*4+2]);
                ga[0][q4*4+3] = fmaf(av0, w4.w, ga[0][q4*4+3]);
                ga[1][q4*4+0] = fmaf(av1, w4.x, ga[1][q4*4+0]);
                ga[1][q4*4+1] = fmaf(av1, w4.y, ga[1][q4*4+1]);
                ga[1][q4*4+2] = fmaf(av1, w4.z, ga[1][q4*4+2]);
                ga[1][q4*4+3] = fmaf(av1, w4.w, ga[1][q4*4+3]);
            }
        }
    }
    const int wb = s ? 83 : -6;
    #pragma unroll
    for (int j = 0; j < 2; ++j) {
        int w = wb + 6 + row0 + j;
        float* dst = nullptr;
        if (s == 0) {
            if (w < 6) dst = g_gxe + ((size_t)b*12 + w)*GDIM + g0;
        } else {
            if (w == 89)      dst = g_gxg + ((size_t)b*TOT + (i + 89))*GDIM + g0;
            else if (w < SEQ) dst = g_gxe + ((size_t)b*12 + (w - 84))*GDIM + g0;
        }
        if (dst) {
            *(float4*)(dst)     = *(const float4*)&ga[j][0];
            *(float4*)(dst + 4) = *(const float4*)&ga[j][4];
            *(float4*)(dst + 8) = *(const float4*)&ga[j][8];
        }
    }
}

// -------------------------------------------------------------- recurrence
// grid 512, 128 threads (2 waves): thread j owns hidden unit j, all 3 gates.
// Wh rows live in 12 named ext_vector_type(32) values = 384 floats -> these are
// first-class SSA vectors, NOT allocas, so they CANNOT be demoted to scratch.
// launch_bounds(128,1) -> 512-VGPR budget (~430 used). One barrier/t, ping-pong H.

#define GRU_LOAD(RV,ZV,NV,OFF) \
    _Pragma("unroll") \
    for (int c = 0; c < 32; ++c) { \
        RV[c] = WhT[(OFF+c)*GDIM + j]; \
        ZV[c] = WhT[(OFF+c)*GDIM + DM + j]; \
        NV[c] = WhT[(OFF+c)*GDIM + 2*DM + j]; \
    }

#define GRU_DOT(RV,ZV,NV,OFF) \
    _Pragma("unroll") \
    for (int c = 0; c < 32; c += 4) { \
        float4 h4 = *(const float4*)(Hc + OFF + c); \
        ar = fmaf(h4.x, RV[c],   ar); az = fmaf(h4.x, ZV[c],   az); an = fmaf(h4.x, NV[c],   an); \
        ar = fmaf(h4.y, RV[c+1], ar); az = fmaf(h4.y, ZV[c+1], az); an = fmaf(h4.y, NV[c+1], an); \
        ar = fmaf(h4.z, RV[c+2], ar); az = fmaf(h4.z, ZV[c+2], az); an = fmaf(h4.z, NV[c+2], an); \
        ar = fmaf(h4.w, RV[c+3], ar); az = fmaf(h4.w, ZV[c+3], az); an = fmaf(h4.w, NV[c+3], an); \
    }

__launch_bounds__(128, 1)
__global__ void gru_rec(int i, const float* __restrict__ gbh,
                        const float* __restrict__ fc_w, const float* __restrict__ fc_b,
                        float* __restrict__ out) {
    __shared__ __align__(16) float H[2][DM];
    const int j = threadIdx.x;
    const int b = blockIdx.x;
    const float* WhT = g_wT + OFF_WHT;

    f32x32 r0v, r1v, r2v, r3v, z0v, z1v, z2v, z3v, n0v, n1v, n2v, n3v;
    GRU_LOAD(r0v, z0v, n0v, 0)
    GRU_LOAD(r1v, z1v, n1v, 32)
    GRU_LOAD(r2v, z2v, n2v, 64)
    GRU_LOAD(r3v, z3v, n3v, 96)
    const float bhr = gbh[j], bhz = gbh[DM + j], bhn = gbh[2*DM + j];
    float h = 0.f;
    H[0][j] = 0.f;
    __syncthreads();

    const float* gxg_b = g_gxg + (size_t)b*TOT*GDIM;
    const float* gxe_b = g_gxe + (size_t)b*12*GDIM;
    auto gp = [&](int t) -> const float* {
        return (t < 6)  ? (gxe_b + t*GDIM)
             : (t < 90) ? (gxg_b + (size_t)(i + t)*GDIM)
                        : (gxe_b + (t - 84)*GDIM);
    };

    const float* g0p = gp(0);
    float gxr = g0p[j], gxz = g0p[DM + j], gxn = g0p[2*DM + j];
    for (int t = 0; t < SEQ; ++t) {
        float nxr = 0.f, nxz = 0.f, nxn = 0.f;
        if (t + 1 < SEQ) {                      // prefetch next t's gate inputs
            const float* gq = gp(t + 1);
            nxr = gq[j]; nxz = gq[DM + j]; nxn = gq[2*DM + j];
        }
        const float* Hc = H[t & 1];
        float ar = bhr, az = bhz, an = bhn;     // 3 chains, 6-cyc dep distance
        GRU_DOT(r0v, z0v, n0v, 0)
        GRU_DOT(r1v, z1v, n1v, 32)
        GRU_DOT(r2v, z2v, n2v, 64)
        GRU_DOT(r3v, z3v, n3v, 96)
        float r = 1.f/(1.f + __expf(-(gxr + ar)));
        float z = 1.f/(1.f + __expf(-(gxz + az)));
        float xn = gxn + r*an;
        float e2 = __expf(2.f*xn);
        float n = 1.f - 2.f/(e2 + 1.f);         // tanh(xn)
        h = (1.f - z)*n + z*h;
        H[(t+1) & 1][j] = h;
        __syncthreads();
        gxr = nxr; gxz = nxz; gxn = nxn;
    }

    if (j < CIN) {
        float p = fc_b[j];
        const float* Hf = H[SEQ & 1];           // SEQ even -> H[0]
        #pragma unroll
        for (int d = 0; d < DM; ++d) p = fmaf(fc_w[j*DM + d], Hf[d], p);
        out[(b*PRED + i)*CIN + j] = p;
    }
}

// ---------------------------------------------------------------- launch
extern "C" void kernel_launch(void* const* d_in, const int* in_sizes, int n_in,
                              void* d_out, int out_size, void* d_ws, size_t ws_size,
                              hipStream_t stream) {
    const float* x_enc  = (const float*)d_in[0];
    const int*   y_mark = (const int*)d_in[2];
    const float* hour_e = (const float*)d_in[3];
    const float* wk_e   = (const float*)d_in[4];
    const float* day_e  = (const float*)d_in[5];
    const float* mon_e  = (const float*)d_in[6];
    const float* W_val  = (const float*)d_in[7];
    const float* b_val  = (const float*)d_in[8];
    const float* c1w    = (const float*)d_in[9];
    const float* c1b    = (const float*)d_in[10];
    const float* c2w    = (const float*)d_in[11];
    const float* c2b    = (const float*)d_in[12];
    const float* c3w    = (const float*)d_in[13];
    const float* c3b    = (const float*)d_in[14];
    const float* Wi     = (const float*)d_in[15];
    const float* Wh     = (const float*)d_in[16];
    const float* gbi    = (const float*)d_in[17];
    const float* gbh    = (const float*)d_in[18];
    const float* fcw    = (const float*)d_in[19];
    const float* fcb    = (const float*)d_in[20];
    float* out = (float*)d_out;

    prep_weights<<<(W_TOTAL + 255)/256, 256, 0, stream>>>(c1w, c2w, c3w, Wi, Wh);

    init_kernel<<<dim3(B_SZ, 2), 256, 0, stream>>>(x_enc, y_mark,
        hour_e, wk_e, day_e, mon_e, W_val, b_val, c1b, c2b, c3b, gbi);

    for (int i = 0; i < PRED; ++i) {
        step_kernel<<<B_SZ, 256, 0, stream>>>(i, x_enc, y_mark,
            hour_e, wk_e, day_e, mon_e, W_val, b_val, c1b, c2b, c3b, gbi, out);
        gru_rec<<<B_SZ, 128, 0, stream>>>(i, gbh, fcw, fcb, out);
    }
}

// Round 8
// 11283.981 us; speedup vs baseline: 1.6790x; 1.6746x over previous
//
#include <hip/hip_runtime.h>

#define B_SZ 512
#define SEQ 96
#define PRED 48
#define TOT 144
#define CIN 7
#define DM 128
#define GDIM 384
#define KS 5

#define CSTR 132              // LDS row stride for activation buffers
#define ASUB (20*CSTR)        // floats per 20-row sub-buffer
#define WROW 136              // swizzled LDS weight row (128 + pad)
#define SWZ(o) ((o) + ((((o) >> 6)) << 2))   // bank swizzle: pad 4 every 64 floats

#define W_CONV (KS*DM*DM)            // 81920 per conv layer (layout [k][c][o])
#define OFF_WIT (3*W_CONV)           // WiT [c][384]
#define OFF_WHT (3*W_CONV + DM*GDIM) // WhT [c][384]
#define W_TOTAL (3*W_CONV + 2*DM*GDIM)

#define NBB 2                 // batches per gru block

// Device-global scratch
__device__ float g_gxg[(size_t)B_SZ*TOT*GDIM];  // invariant gx cache, [b][p][384]
__device__ float g_gxe[B_SZ*12*GDIM];           // per-step edge gx, [b][12][384]
__device__ float g_wT[W_TOTAL];                 // transposed weights

// ---------------------------------------------------------------- prep
__global__ void prep_weights(const float* __restrict__ w1, const float* __restrict__ w2,
                             const float* __restrict__ w3, const float* __restrict__ Wi,
                             const float* __restrict__ Wh) {
    int tid = blockIdx.x*256 + threadIdx.x;
    if (tid < 3*W_CONV) {
        int l = tid / W_CONV, r = tid % W_CONV;
        int o = r & 127, c = (r >> 7) & 127, k = r >> 14;   // r = (k*128+c)*128+o
        const float* w = (l==0) ? w1 : ((l==1) ? w2 : w3);
        g_wT[tid] = w[o*(DM*KS) + c*KS + k];                 // src [o][c][k]
    } else if (tid < W_TOTAL) {
        int r = tid - 3*W_CONV;
        int m = r / (DM*GDIM), q = r % (DM*GDIM);
        int g = q % GDIM, c = q / GDIM;                      // dst [c][g]
        const float* W = (m==0) ? Wi : Wh;
        g_wT[tid] = W[g*DM + c];                             // src [g][c]
    }
}

// ---------------------------------------------------------------- fma helper
template<int NJ>
__device__ __forceinline__ void fma8(float (&acc)[NJ][8], int j, float a,
                                     const float4& wA, const float4& wB) {
    acc[j][0] = fmaf(a, wA.x, acc[j][0]);
    acc[j][1] = fmaf(a, wA.y, acc[j][1]);
    acc[j][2] = fmaf(a, wA.z, acc[j][2]);
    acc[j][3] = fmaf(a, wA.w, acc[j][3]);
    acc[j][4] = fmaf(a, wB.x, acc[j][4]);
    acc[j][5] = fmaf(a, wB.y, acc[j][5]);
    acc[j][6] = fmaf(a, wB.z, acc[j][6]);
    acc[j][7] = fmaf(a, wB.w, acc[j][7]);
}

// stage 8 channels of conv weights (swizzled) into wbuf — 256-thread version
__device__ __forceinline__ void stage_conv_chunk(float* __restrict__ wbuf,
                                                 const float* __restrict__ wT,
                                                 int cc, int tid) {
    const int cj = tid >> 5, oo = (tid & 31) * 4;
    #pragma unroll
    for (int k = 0; k < KS; ++k)
        *(float4*)(wbuf + (k*8 + cj)*WROW + SWZ(oo)) =
            *(const float4*)(wT + (k*DM + cc*8 + cj)*DM + oo);
}

// Chunked in-place conv layer (init kernel, 256 threads).
template<int NJ>
__device__ __forceinline__ void conv_layer_chunked(float* __restrict__ buf,
                                                   float* __restrict__ wbuf,
                                                   const float* __restrict__ wT,
                                                   const float* __restrict__ bias,
                                                   int nrow, int winO, int tid) {
    const int og = tid & 15, ttg = tid >> 4;
    const int o0 = og*8, so0 = SWZ(o0), r0 = ttg*NJ;
    const bool act = (r0 < nrow);
    float acc[NJ][8];
    #pragma unroll
    for (int u = 0; u < 8; ++u) {
        float bv = bias[o0+u];
        #pragma unroll
        for (int j = 0; j < NJ; ++j) acc[j][u] = bv;
    }
    for (int cc = 0; cc < DM/8; ++cc) {
        __syncthreads();
        stage_conv_chunk(wbuf, wT, cc, tid);
        __syncthreads();
        if (act) {
            const int c0 = cc*8;
            #pragma unroll
            for (int cj = 0; cj < 8; cj += 2) {
                float2 a2[NJ+4];
                #pragma unroll
                for (int m = 0; m < NJ+4; ++m)
                    a2[m] = *(const float2*)(buf + (r0+m)*CSTR + c0 + cj);
                #pragma unroll
                for (int k = 0; k < KS; ++k) {
                    const float4 wA0 = *(const float4*)(wbuf + (k*8+cj)*WROW + so0);
                    const float4 wB0 = *(const float4*)(wbuf + (k*8+cj)*WROW + so0 + 4);
                    const float4 wA1 = *(const float4*)(wbuf + (k*8+cj+1)*WROW + so0);
                    const float4 wB1 = *(const float4*)(wbuf + (k*8+cj+1)*WROW + so0 + 4);
                    #pragma unroll
                    for (int j = 0; j < NJ; ++j) {
                        fma8(acc, j, a2[j+k].x, wA0, wB0);
                        fma8(acc, j, a2[j+k].y, wA1, wB1);
                    }
                }
            }
        }
    }
    __syncthreads();
    if (act) {
        #pragma unroll
        for (int j = 0; j < NJ; ++j) {
            int q = r0 + j, w = winO + q;
            bool valid = (w >= 0) && (w < SEQ);
            #pragma unroll
            for (int u = 0; u < 8; ++u)
                buf[q*CSTR + o0+u] = valid ? fmaxf(acc[j][u], 0.f) : 0.f;
        }
    }
    __syncthreads();
}

// ------------------------------------------------------------- init kernel
// Step 0's full conv cascade; stores invariant gx rows w in [6,90) to g_gxg[b][w].
__launch_bounds__(256, 3)
__global__ void init_kernel(const float* __restrict__ x_enc,
                            const int* __restrict__ y_mark,
                            const float* __restrict__ hour_e, const float* __restrict__ wk_e,
                            const float* __restrict__ day_e, const float* __restrict__ mon_e,
                            const float* __restrict__ W_val, const float* __restrict__ b_val,
                            const float* __restrict__ b1, const float* __restrict__ b2,
                            const float* __restrict__ b3, const float* __restrict__ gbi) {
    __shared__ float buf[60*CSTR];
    __shared__ float wbuf[KS*8*WROW];
    const int tid = threadIdx.x;
    const int b = blockIdx.x;
    const int cs = blockIdx.y * 48;

    for (int e = tid; e < 60*DM; e += 256) {
        int q = e >> 7, d = e & 127;
        int w = cs - 6 + q;
        float v = 0.f;
        if (w >= 0 && w < SEQ) {
            const float* xr = x_enc + (b*SEQ + w)*CIN;
            v = b_val[d];
            #pragma unroll
            for (int c = 0; c < CIN; ++c) v = fmaf(xr[c], W_val[d*CIN + c], v);
            const int* ym = y_mark + (b*TOT + w)*4;
            v += hour_e[ym[0]*DM + d] + wk_e[ym[1]*DM + d]
               + day_e[ym[2]*DM + d] + mon_e[ym[3]*DM + d];
        }
        buf[q*CSTR + d] = v;
    }
    conv_layer_chunked<4>(buf, wbuf, g_wT,            b1, 56, cs - 4, tid);
    conv_layer_chunked<4>(buf, wbuf, g_wT + W_CONV,   b2, 52, cs - 2, tid);
    conv_layer_chunked<3>(buf, wbuf, g_wT + 2*W_CONV, b3, 48, cs,     tid);

    const int og = tid & 15, ttg = tid >> 4;
    const int g0 = og*24, r0 = ttg*3;
    const float* WiT = g_wT + OFF_WIT;
    float ga[3][24];
    #pragma unroll
    for (int e = 0; e < 24; ++e) {
        float bv = gbi[g0+e];
        #pragma unroll
        for (int j = 0; j < 3; ++j) ga[j][e] = bv;
    }
    for (int cc = 0; cc < DM/8; ++cc) {
        __syncthreads();
        #pragma unroll
        for (int s = 0; s < 3; ++s)
            ((float4*)wbuf)[s*256 + tid] = ((const float4*)(WiT + cc*8*GDIM))[s*256 + tid];
        __syncthreads();
        const int c0 = cc*8;
        #pragma unroll
        for (int cj = 0; cj < 8; cj += 2) {
            float2 a2[3];
            #pragma unroll
            for (int m = 0; m < 3; ++m)
                a2[m] = *(const float2*)(buf + (r0+m)*CSTR + c0 + cj);
            float4 w4[6];
            #pragma unroll
            for (int q = 0; q < 6; ++q)
                w4[q] = *(const float4*)(wbuf + cj*GDIM + g0 + q*4);
            const float* wv = (const float*)w4;
            #pragma unroll
            for (int j = 0; j < 3; ++j)
                #pragma unroll
                for (int e = 0; e < 24; ++e)
                    ga[j][e] = fmaf(a2[j].x, wv[e], ga[j][e]);
            #pragma unroll
            for (int q = 0; q < 6; ++q)
                w4[q] = *(const float4*)(wbuf + (cj+1)*GDIM + g0 + q*4);
            #pragma unroll
            for (int j = 0; j < 3; ++j)
                #pragma unroll
                for (int e = 0; e < 24; ++e)
                    ga[j][e] = fmaf(a2[j].y, wv[e], ga[j][e]);
        }
    }
    #pragma unroll
    for (int j = 0; j < 3; ++j) {
        int w = cs + r0 + j;
        if (w >= 6 && w < 90) {
            float* gxo = g_gxg + ((size_t)b*TOT + w)*GDIM + g0;
            #pragma unroll
            for (int q = 0; q < 6; ++q)
                *(float4*)(gxo + q*4) = *(const float4*)&ga[j][q*4];
        }
    }
}

// ------------------------------------------------------------- step layer
// 256 threads, 2 sub-buffers (left/right edge of one batch). R rows/sub.
template<int NJ>
__device__ __forceinline__ void mlayer(float* __restrict__ abuf, float* __restrict__ wbuf,
                                       const float* __restrict__ wT,
                                       const float* __restrict__ bias,
                                       int R, int off, int tid) {
    const int og = tid & 15, ttg = tid >> 4;     // og 0..15, ttg 0..15
    const int o0 = og*8, so0 = SWZ(o0);
    const int m0 = ttg * NJ;
    const bool act = (m0 < 2*R);
    int s = 0, r0 = 0;
    if (act) { s = m0 / R; r0 = m0 - s*R; }      // NJ divides R -> rows don't span subs
    float* in = abuf + s*ASUB;
    float acc[NJ][8];
    #pragma unroll
    for (int u = 0; u < 8; ++u) {
        float bv = bias[o0+u];
        #pragma unroll
        for (int j = 0; j < NJ; ++j) acc[j][u] = bv;
    }
    for (int cc = 0; cc < DM/8; ++cc) {
        __syncthreads();
        stage_conv_chunk(wbuf, wT, cc, tid);
        __syncthreads();
        if (act) {
            const int c0 = cc*8;
            #pragma unroll
            for (int cj = 0; cj < 8; cj += 2) {
                float2 a2[NJ+4];
                #pragma unroll
                for (int m = 0; m < NJ+4; ++m)
                    a2[m] = *(const float2*)(in + (r0+m)*CSTR + c0 + cj);
                #pragma unroll
                for (int k = 0; k < KS; ++k) {
                    const float4 wA0 = *(const float4*)(wbuf + (k*8+cj)*WROW + so0);
                    const float4 wB0 = *(const float4*)(wbuf + (k*8+cj)*WROW + so0 + 4);
                    const float4 wA1 = *(const float4*)(wbuf + (k*8+cj+1)*WROW + so0);
                    const float4 wB1 = *(const float4*)(wbuf + (k*8+cj+1)*WROW + so0 + 4);
                    #pragma unroll
                    for (int j = 0; j < NJ; ++j) {
                        fma8(acc, j, a2[j+k].x, wA0, wB0);
                        fma8(acc, j, a2[j+k].y, wA1, wB1);
                    }
                }
            }
        }
    }
    __syncthreads();
    if (act) {
        const int wb = s ? 83 : -6;
        #pragma unroll
        for (int j = 0; j < NJ; ++j) {
            int q = r0 + j, w = wb + off + q;
            bool valid = (w >= 0) && (w < SEQ);
            #pragma unroll
            for (int u = 0; u < 8; ++u)
                in[q*CSTR + o0+u] = valid ? fmaxf(acc[j][u], 0.f) : 0.f;
        }
    }
    __syncthreads();
}

// ------------------------------------------------------------- step kernel
// grid 512, 256 threads. Block handles one batch x both edges (2 subs).
__launch_bounds__(256, 3)
__global__ void step_kernel(int i, const float* __restrict__ x_enc,
                            const int* __restrict__ y_mark,
                            const float* __restrict__ hour_e, const float* __restrict__ wk_e,
                            const float* __restrict__ day_e, const float* __restrict__ mon_e,
                            const float* __restrict__ W_val, const float* __restrict__ b_val,
                            const float* __restrict__ b1, const float* __restrict__ b2,
                            const float* __restrict__ b3, const float* __restrict__ gbi,
                            const float* __restrict__ out) {
    __shared__ float abuf[2*ASUB];     // 21.1 KB
    __shared__ float wbuf[16*GDIM];    // 24.6 KB (conv chunks use 5440 floats of it)
    const int tid = threadIdx.x;
    const int b = blockIdx.x;

    // ---- embedding: 2 subs x 20 rows x 128
    for (int e = tid; e < 2*20*DM; e += 256) {
        int s = e / (20*DM);
        int rem = e - s*(20*DM);
        int q = rem >> 7, d = rem & 127;
        int wb = s ? 83 : -6;
        int w = wb + q;
        float v = 0.f;
        if (w >= 0 && w < SEQ) {
            int p = i + w;
            const float* xr = (p < SEQ) ? (x_enc + (b*SEQ + p)*CIN)
                                        : (out + (b*PRED + (p - SEQ))*CIN);
            v = b_val[d];
            #pragma unroll
            for (int c = 0; c < CIN; ++c) v = fmaf(xr[c], W_val[d*CIN + c], v);
            const int* ym = y_mark + (b*TOT + p)*4;
            v += hour_e[ym[0]*DM + d] + wk_e[ym[1]*DM + d]
               + day_e[ym[2]*DM + d] + mon_e[ym[3]*DM + d];
        }
        abuf[s*ASUB + q*CSTR + d] = v;
    }
    mlayer<2>(abuf, wbuf, g_wT,            b1, 16, 2, tid);  // c1: 32 rows
    mlayer<2>(abuf, wbuf, g_wT + W_CONV,   b2, 12, 4, tid);  // c2: 24 rows
    mlayer<1>(abuf, wbuf, g_wT + 2*W_CONV, b3,  8, 6, tid);  // c3: 16 rows

    // ---- gx: 16 c3 rows; thread tile = 2 rows x 12 g
    const int mp = tid >> 5;                 // 0..7 row-pairs
    const int g0 = (tid & 31) * 12;
    const int s = mp >> 2;                   // sub-buffer
    const int row0 = (2*mp) & 7;
    const float* a0p = abuf + s*ASUB + row0*CSTR;
    const float* a1p = a0p + CSTR;
    const float* WiT = g_wT + OFF_WIT;
    float ga[2][12];
    #pragma unroll
    for (int e = 0; e < 12; ++e) { float bv = gbi[g0+e]; ga[0][e] = bv; ga[1][e] = bv; }
    for (int cc = 0; cc < 8; ++cc) {
        __syncthreads();
        for (int x = tid; x < 16*GDIM/4; x += 256)
            ((float4*)wbuf)[x] = ((const float4*)(WiT + cc*16*GDIM))[x];
        __syncthreads();
        #pragma unroll
        for (int c = 0; c < 16; ++c) {
            float av0 = a0p[cc*16 + c];
            float av1 = a1p[cc*16 + c];
            const float* wr = wbuf + c*GDIM + g0;
            #pragma unroll
            for (int q4 = 0; q4 < 3; ++q4) {
                float4 w4 = *(const float4*)(wr + q4*4);
                ga[0][q4*4+0] = fmaf(av0, w4.x, ga[0][q4*4+0]);
                ga[0][q4*4+1] = fmaf(av0, w4.y, ga[0][q4*4+1]);
                ga[0][q4*4+2] = fmaf(av0, w4.z, ga[0][q4*4+2]);
                ga[0][q4*4+3] = fmaf(av0, w4.w, ga[0][q4*4+3]);
                ga[1][q4*4+0] = fmaf(av1, w4.x, ga[1][q4*4+0]);
                ga[1][q4*4+1] = fmaf(av1, w4.y, ga[1][q4*4+1]);
                ga[1][q4*4+2] = fmaf(av1, w4.z, ga[1][q4*4+2]);
                ga[1][q4*4+3] = fmaf(av1, w4.w, ga[1][q4*4+3]);
            }
        }
    }
    const int wb = s ? 83 : -6;
    #pragma unroll
    for (int j = 0; j < 2; ++j) {
        int w = wb + 6 + row0 + j;
        float* dst = nullptr;
        if (s == 0) {
            if (w < 6) dst = g_gxe + ((size_t)b*12 + w)*GDIM + g0;
        } else {
            if (w == 89)      dst = g_gxg + ((size_t)b*TOT + (i + 89))*GDIM + g0;
            else if (w < SEQ) dst = g_gxe + ((size_t)b*12 + (w - 84))*GDIM + g0;
        }
        if (dst) {
            *(float4*)(dst)     = *(const float4*)&ga[j][0];
            *(float4*)(dst + 4) = *(const float4*)&ga[j][4];
            *(float4*)(dst + 8) = *(const float4*)&ga[j][8];
        }
    }
}

// -------------------------------------------------------------- recurrence v4
// grid 256 (NBB=2 batches/block), 512 threads = (unit j in [0,128)) x (c-slice
// s in [0,4)). Thread holds Wh slices whr/whz/whn[32] (96 floats — small arrays
// that the allocator actually promotes, unlike the 128/384-float versions).
// Per t: slice dots -> LDS partials -> 256 combine threads do gate math.
__launch_bounds__(512, 2)
__global__ void gru_rec(int i, const float* __restrict__ gbh,
                        const float* __restrict__ fc_w, const float* __restrict__ fc_b,
                        float* __restrict__ out) {
    __shared__ __align__(16) float H[2][NBB][DM];     // ping-pong hidden state
    __shared__ float P[3][4][NBB][DM];                // partials [gate][slice][b][j]
    const int tid = threadIdx.x;
    const int j = tid & 127, s = tid >> 7;            // per-wave: j consecutive, s uniform
    const int b0 = blockIdx.x * NBB;

    // Wh slices for (unit j, c in [32s, 32s+32)), all 3 gates
    float whr[32], whz[32], whn[32];
    {
        const float* Wp = g_wT + OFF_WHT + (size_t)(32*s)*GDIM + j;
        #pragma unroll
        for (int c = 0; c < 32; ++c) {
            whr[c] = Wp[c*GDIM];
            whz[c] = Wp[c*GDIM + DM];
            whn[c] = Wp[c*GDIM + 2*DM];
        }
    }

    // combine-thread role: tid < 256 -> (cb = tid>>7, cj = tid&127)
    const int cb = s & 1, cj = j;
    const bool comb = (tid < NBB*DM);
    float bhr = 0.f, bhz = 0.f, bhn = 0.f;
    if (comb) {
        bhr = gbh[cj]; bhz = gbh[DM + cj]; bhn = gbh[2*DM + cj];
        H[0][cb][cj] = 0.f;
    }

    const float* gxg_b0 = g_gxg + (size_t)(b0)*TOT*GDIM;
    const float* gxe_b0 = g_gxe + (size_t)(b0)*12*GDIM;
    auto gp = [&](int t, int bb) -> const float* {
        return (t < 6)  ? (gxe_b0 + (size_t)bb*12*GDIM + t*GDIM)
             : (t < 90) ? (gxg_b0 + (size_t)bb*TOT*GDIM + (size_t)(i + t)*GDIM)
                        : (gxe_b0 + (size_t)bb*12*GDIM + (t - 84)*GDIM);
    };

    float gxr = 0.f, gxz = 0.f, gxn = 0.f;
    if (comb) {
        const float* g0p = gp(0, cb);
        gxr = g0p[cj]; gxz = g0p[DM + cj]; gxn = g0p[2*DM + cj];
    }
    __syncthreads();

    for (int t = 0; t < SEQ; ++t) {
        // ---- slice dots: 2 batches x 3 gates x 32 MACs
        #pragma unroll
        for (int b = 0; b < NBB; ++b) {
            const float* Hc = &H[t & 1][b][32*s];     // wave-uniform -> broadcast
            float ar = 0.f, az = 0.f, an = 0.f;
            #pragma unroll
            for (int c = 0; c < 32; c += 4) {
                float4 h4 = *(const float4*)(Hc + c);
                ar = fmaf(h4.x, whr[c],   ar); az = fmaf(h4.x, whz[c],   az); an = fmaf(h4.x, whn[c],   an);
                ar = fmaf(h4.y, whr[c+1], ar); az = fmaf(h4.y, whz[c+1], az); an = fmaf(h4.y, whn[c+1], an);
                ar = fmaf(h4.z, whr[c+2], ar); az = fmaf(h4.z, whz[c+2], az); an = fmaf(h4.z, whn[c+2], an);
                ar = fmaf(h4.w, whr[c+3], ar); az = fmaf(h4.w, whz[c+3], az); an = fmaf(h4.w, whn[c+3], an);
            }
            P[0][s][b][j] = ar;     // stride-1 in j -> conflict-free
            P[1][s][b][j] = az;
            P[2][s][b][j] = an;
        }
        __syncthreads();
        // ---- combine + gate math (waves 0-3 only; uniform per wave)
        if (comb) {
            float ar = bhr + ((P[0][0][cb][cj] + P[0][1][cb][cj]) + (P[0][2][cb][cj] + P[0][3][cb][cj]));
            float az = bhz + ((P[1][0][cb][cj] + P[1][1][cb][cj]) + (P[1][2][cb][cj] + P[1][3][cb][cj]));
            float an = bhn + ((P[2][0][cb][cj] + P[2][1][cb][cj]) + (P[2][2][cb][cj] + P[2][3][cb][cj]));
            float r = 1.f/(1.f + __expf(-(gxr + ar)));
            float z = 1.f/(1.f + __expf(-(gxz + az)));
            float xn = gxn + r*an;
            float e2 = __expf(2.f*xn);
            float n = 1.f - 2.f/(e2 + 1.f);           // tanh(xn)
            float h = (1.f - z)*n + z*H[t & 1][cb][cj];
            H[(t + 1) & 1][cb][cj] = h;
            if (t + 1 < SEQ) {                        // prefetch next t's gx
                const float* gq = gp(t + 1, cb);
                gxr = gq[cj]; gxz = gq[DM + cj]; gxn = gq[2*DM + cj];
            }
        }
        __syncthreads();
    }

    // ---- pred = h @ fc_w^T + fc_b (SEQ even -> final state in H[0])
    if (tid < NBB*CIN) {
        int bb = tid / CIN, o = tid % CIN;
        float p = fc_b[o];
        const float* Hf = H[0][bb];
        #pragma unroll
        for (int d = 0; d < DM; ++d) p = fmaf(fc_w[o*DM + d], Hf[d], p);
        out[((b0 + bb)*PRED + i)*CIN + o] = p;
    }
}

// ---------------------------------------------------------------- launch
extern "C" void kernel_launch(void* const* d_in, const int* in_sizes, int n_in,
                              void* d_out, int out_size, void* d_ws, size_t ws_size,
                              hipStream_t stream) {
    const float* x_enc  = (const float*)d_in[0];
    const int*   y_mark = (const int*)d_in[2];
    const float* hour_e = (const float*)d_in[3];
    const float* wk_e   = (const float*)d_in[4];
    const float* day_e  = (const float*)d_in[5];
    const float* mon_e  = (const float*)d_in[6];
    const float* W_val  = (const float*)d_in[7];
    const float* b_val  = (const float*)d_in[8];
    const float* c1w    = (const float*)d_in[9];
    const float* c1b    = (const float*)d_in[10];
    const float* c2w    = (const float*)d_in[11];
    const float* c2b    = (const float*)d_in[12];
    const float* c3w    = (const float*)d_in[13];
    const float* c3b    = (const float*)d_in[14];
    const float* Wi     = (const float*)d_in[15];
    const float* Wh     = (const float*)d_in[16];
    const float* gbi    = (const float*)d_in[17];
    const float* gbh    = (const float*)d_in[18];
    const float* fcw    = (const float*)d_in[19];
    const float* fcb    = (const float*)d_in[20];
    float* out = (float*)d_out;

    prep_weights<<<(W_TOTAL + 255)/256, 256, 0, stream>>>(c1w, c2w, c3w, Wi, Wh);

    init_kernel<<<dim3(B_SZ, 2), 256, 0, stream>>>(x_enc, y_mark,
        hour_e, wk_e, day_e, mon_e, W_val, b_val, c1b, c2b, c3b, gbi);

    for (int i = 0; i < PRED; ++i) {
        step_kernel<<<B_SZ, 256, 0, stream>>>(i, x_enc, y_mark,
            hour_e, wk_e, day_e, mon_e, W_val, b_val, c1b, c2b, c3b, gbi, out);
        gru_rec<<<B_SZ/NBB, 512, 0, stream>>>(i, gbh, fcw, fcb, out);
    }
}